// Round 3
// baseline (1836.146 us; speedup 1.0000x reference)
//
#include <hip/hip_runtime.h>
#include <math.h>

// ---------------- edge dtype detection ----------------
// edge_index may be int32 or int64 (harness/JAX x64 ambiguity). For int64
// little-endian values < 2^31, every odd 32-bit word is zero. For int32
// random node ids, ~all odd words are nonzero. Count nonzero among 1024
// odd words; zero count => int64.

__global__ void detect_kernel(const int* __restrict__ ei, int* __restrict__ flag) {
    int i = threadIdx.x;  // one block of 1024
    if (ei[2 * i + 1] != 0) atomicAdd(flag, 1);
}

// ---------------- CSR build ----------------

__global__ void hist_kernel(const int* __restrict__ ei, int e,
                            const int* __restrict__ flag, int* __restrict__ deg) {
    int i = blockIdx.x * blockDim.x + threadIdx.x;
    if (i < e) {
        bool is64 = (*flag == 0);
        int d = is64 ? ei[2 * e + 2 * i] : ei[e + i];
        atomicAdd(&deg[d], 1);
    }
}

__global__ void dinv_kernel(const int* __restrict__ deg, float* __restrict__ dinv, int n) {
    int i = blockIdx.x * blockDim.x + threadIdx.x;
    if (i < n) dinv[i] = rsqrtf(1.0f + (float)deg[i]);
}

// Block of 256 threads scans 1024 elements (4/thread). Writes per-element
// exclusive prefix (within block) and the block total.
__global__ void scan_partial(const int* __restrict__ deg, int* __restrict__ out,
                             int* __restrict__ bsums, int n) {
    __shared__ int sh[256];
    int t = threadIdx.x;
    int base = blockIdx.x * 1024 + t * 4;
    int v0 = 0, v1 = 0, v2 = 0, v3 = 0;
    if (base + 0 < n) v0 = deg[base + 0];
    if (base + 1 < n) v1 = deg[base + 1];
    if (base + 2 < n) v2 = deg[base + 2];
    if (base + 3 < n) v3 = deg[base + 3];
    int s = v0 + v1 + v2 + v3;
    sh[t] = s;
    __syncthreads();
    for (int off = 1; off < 256; off <<= 1) {
        int x = (t >= off) ? sh[t - off] : 0;
        __syncthreads();
        sh[t] += x;
        __syncthreads();
    }
    int excl = sh[t] - s;
    if (base + 0 < n) out[base + 0] = excl;  excl += v0;
    if (base + 1 < n) out[base + 1] = excl;  excl += v1;
    if (base + 2 < n) out[base + 2] = excl;  excl += v2;
    if (base + 3 < n) out[base + 3] = excl;
    if (t == 255) bsums[blockIdx.x] = sh[255];
}

// Single block, inclusive scan of block sums (nb <= 1024).
__global__ void scan_bsums(int* bsums, int nb) {
    __shared__ int sh[1024];
    int t = threadIdx.x;
    sh[t] = (t < nb) ? bsums[t] : 0;
    __syncthreads();
    for (int off = 1; off < 1024; off <<= 1) {
        int x = (t >= off) ? sh[t - off] : 0;
        __syncthreads();
        sh[t] += x;
        __syncthreads();
    }
    if (t < nb) bsums[t] = sh[t];
}

__global__ void scan_add(int* __restrict__ row_ptr, const int* __restrict__ bsums,
                         int n, int nb) {
    int i = blockIdx.x * blockDim.x + threadIdx.x;
    if (i < n) {
        int b = i >> 10;
        if (b > 0) row_ptr[i] += bsums[b - 1];
    } else if (i == n) {
        row_ptr[n] = bsums[nb - 1];
    }
}

__global__ void build_col(const int* __restrict__ ei, int e, const int* __restrict__ flag,
                          int* __restrict__ cursor, int* __restrict__ col) {
    int i = blockIdx.x * blockDim.x + threadIdx.x;
    if (i < e) {
        bool is64 = (*flag == 0);
        int s = is64 ? ei[2 * i]         : ei[i];
        int d = is64 ? ei[2 * e + 2 * i] : ei[e + i];
        int pos = atomicAdd(&cursor[d], 1);
        col[pos] = s;
    }
}

// ---------------- GEMM: out[n,CO] = A[n,CI] @ W[CI,CO], optional *dinv[row] ----------------
// 256 threads; thread tile 8 rows x 4 cols; full W staged in LDS (<=32 KB).

template <int CI, int CO, bool SCALE>
__global__ __launch_bounds__(256) void gemm_kernel(const float* __restrict__ A,
                                                   const float* __restrict__ W,
                                                   const float* __restrict__ dinv,
                                                   float* __restrict__ out, int n) {
    constexpr int CT = CO / 4;        // threads covering the CO dimension
    constexpr int RG = 256 / CT;      // row-groups per block
    constexpr int BR = RG * 8;        // rows per block
    __shared__ __align__(16) float Wl[CI * CO];
    for (int i = threadIdx.x; i < CI * CO; i += 256) Wl[i] = W[i];
    __syncthreads();

    int ct = threadIdx.x % CT;
    int rg = threadIdx.x / CT;
    int c0 = ct * 4;
    int row0 = blockIdx.x * BR + rg * 8;

    float acc[8][4] = {{0.f}};
    for (int k = 0; k < CI; k += 4) {
        float4 a[8];
#pragma unroll
        for (int r = 0; r < 8; r++) {
            int row = row0 + r;
            if (row < n)
                a[r] = *reinterpret_cast<const float4*>(&A[row * CI + k]);
            else
                a[r] = float4{0.f, 0.f, 0.f, 0.f};
        }
#pragma unroll
        for (int kk = 0; kk < 4; kk++) {
            float4 w = *reinterpret_cast<const float4*>(&Wl[(k + kk) * CO + c0]);
#pragma unroll
            for (int r = 0; r < 8; r++) {
                float av = (kk == 0) ? a[r].x : (kk == 1) ? a[r].y : (kk == 2) ? a[r].z : a[r].w;
                acc[r][0] += av * w.x;
                acc[r][1] += av * w.y;
                acc[r][2] += av * w.z;
                acc[r][3] += av * w.w;
            }
        }
    }
#pragma unroll
    for (int r = 0; r < 8; r++) {
        int row = row0 + r;
        if (row >= n) continue;
        float s = SCALE ? dinv[row] : 1.0f;
        float4 o{acc[r][0] * s, acc[r][1] * s, acc[r][2] * s, acc[r][3] * s};
        *reinterpret_cast<float4*>(&out[row * CO + c0]) = o;
    }
}

// ---------------- Fused gather + self-loop + bias + skip + relu ----------------
// ONE WAVE PER NODE (so a 256-thread block covers exactly 4 nodes, for every F).
// The 64/F sub-groups of a wave split the node's edge list and shfl-reduce.
// hs is pre-scaled: hs = (A@W) * dinv[row].
// out[n,f] = relu( dinv[n]*sum_{j in CSR[n]} hs[col[j],f] + hs[n,f]*dinv[n] + bias[f] (+ sk[n,f]+bsk[f]) )

template <int F>
__global__ __launch_bounds__(256) void gather_combine(
    const float* __restrict__ hs, const int* __restrict__ row_ptr,
    const int* __restrict__ col, const float* __restrict__ dinv,
    const float* __restrict__ bias, const float* __restrict__ sk,
    const float* __restrict__ bsk, float* __restrict__ out, int n) {
    constexpr int EPI = 64 / F;  // edges processed per wave-iteration
    int wid = (blockIdx.x * blockDim.x + threadIdx.x) >> 6;
    int lane = threadIdx.x & 63;
    if (wid >= n) return;
    int sub = lane / F;
    int f = lane & (F - 1);
    int start = row_ptr[wid];
    int end = row_ptr[wid + 1];

    float acc = 0.f;
    int j = start + sub;
    // 2x unrolled: two independent load chains per iteration
    while (j + EPI < end) {
        int c0 = col[j];
        int c1 = col[j + EPI];
        float va = hs[c0 * F + f];
        float vb = hs[c1 * F + f];
        acc += va;
        acc += vb;
        j += 2 * EPI;
    }
    if (j < end) acc += hs[col[j] * F + f];

    if (F <= 32) acc += __shfl_xor(acc, 32);
    if (F <= 16) acc += __shfl_xor(acc, 16);

    float dn = dinv[wid];
    if (lane < F) {
        float v = dn * acc + hs[wid * F + f] * dn + bias[f];
        if (sk) v += sk[wid * F + f] + bsk[f];
        out[wid * F + f] = fmaxf(v, 0.f);
    }
}

// ---------------- Final: out[n] = sigmoid(h3[n,:16] @ Wlin + blin) ----------------

__global__ void final_kernel(const float* __restrict__ h3, const float* __restrict__ Wlin,
                             const float* __restrict__ blin, float* __restrict__ out, int n) {
    int i = blockIdx.x * blockDim.x + threadIdx.x;
    if (i >= n) return;
    float s = blin[0];
#pragma unroll
    for (int f = 0; f < 16; f++) s += h3[i * 16 + f] * Wlin[f];
    out[i] = 1.0f / (1.0f + expf(-s));
}

// ---------------- launch ----------------

extern "C" void kernel_launch(void* const* d_in, const int* in_sizes, int n_in,
                              void* d_out, int out_size, void* d_ws, size_t ws_size,
                              hipStream_t stream) {
    const float* x     = (const float*)d_in[0];
    const int*   ei    = (const int*)d_in[1];
    const float* W1    = (const float*)d_in[2];
    const float* b1    = (const float*)d_in[3];
    const float* W2    = (const float*)d_in[4];
    const float* b2    = (const float*)d_in[5];
    const float* W3    = (const float*)d_in[6];
    const float* b3    = (const float*)d_in[7];
    const float* Wsk02 = (const float*)d_in[8];
    const float* bsk02 = (const float*)d_in[9];
    const float* Wsk13 = (const float*)d_in[10];
    const float* bsk13 = (const float*)d_in[11];
    const float* Wlin  = (const float*)d_in[12];
    const float* blin  = (const float*)d_in[13];

    const int n = in_sizes[0] / 128;
    const int e = in_sizes[1] / 2;   // element count of (2,E) is 2E for int32 and int64 alike

    // workspace carve (256B aligned)
    char* p = (char*)d_ws;
    auto alloc = [&](size_t bytes) {
        void* r = (void*)p;
        p += (bytes + 255) / 256 * 256;
        return r;
    };
    int*   flag    = (int*)alloc(256);
    int*   deg     = (int*)alloc((size_t)n * 4);
    int*   row_ptr = (int*)alloc((size_t)(n + 1) * 4);
    int*   cursor  = (int*)alloc((size_t)n * 4);
    int*   bsums   = (int*)alloc(4096);
    int*   col     = (int*)alloc((size_t)e * 4);
    float* dinv    = (float*)alloc((size_t)n * 4);
    float* h1      = (float*)alloc((size_t)n * 64 * 4);
    float* h2      = (float*)alloc((size_t)n * 32 * 4);
    float* h3      = (float*)alloc((size_t)n * 16 * 4);
    float* pre     = (float*)alloc((size_t)n * 64 * 4);  // reused per layer (pre | skip)

    auto cdiv = [](int a, int b) { return (a + b - 1) / b; };
    const int nb = cdiv(n, 1024);

    // dtype flag + degrees + dinv + CSR
    hipMemsetAsync(flag, 0, 4, stream);
    hipMemsetAsync(deg, 0, (size_t)n * 4, stream);
    detect_kernel<<<1, 1024, 0, stream>>>(ei, flag);
    hist_kernel<<<cdiv(e, 256), 256, 0, stream>>>(ei, e, flag, deg);
    dinv_kernel<<<cdiv(n, 256), 256, 0, stream>>>(deg, dinv, n);
    scan_partial<<<nb, 256, 0, stream>>>(deg, row_ptr, bsums, n);
    scan_bsums<<<1, 1024, 0, stream>>>(bsums, nb);
    scan_add<<<cdiv(n + 1, 256), 256, 0, stream>>>(row_ptr, bsums, n, nb);
    hipMemcpyAsync(cursor, row_ptr, (size_t)n * 4, hipMemcpyDeviceToDevice, stream);
    build_col<<<cdiv(e, 256), 256, 0, stream>>>(ei, e, flag, cursor, col);

    // NOTE: gather_combine is ONE WAVE PER NODE -> grid is always cdiv(n, 4)
    // (4 waves per 256-thread block), independent of F. (Round-2 bug: /8, /16.)

    // layer 1: h1 = relu(conv(x, W1, b1))
    gemm_kernel<128, 64, true><<<cdiv(n, 128), 256, 0, stream>>>(x, W1, dinv, pre, n);
    gather_combine<64><<<cdiv(n, 4), 256, 0, stream>>>(pre, row_ptr, col, dinv, b1,
                                                       nullptr, nullptr, h1, n);

    // layer 2: h2 = relu(conv(h1, W2, b2) + x@Wsk02 + bsk02)
    gemm_kernel<64, 32, true><<<cdiv(n, 256), 256, 0, stream>>>(h1, W2, dinv, pre, n);
    gemm_kernel<128, 32, false><<<cdiv(n, 256), 256, 0, stream>>>(x, Wsk02, nullptr,
                                                                  pre + (size_t)n * 32, n);
    gather_combine<32><<<cdiv(n, 4), 256, 0, stream>>>(pre, row_ptr, col, dinv, b2,
                                                       pre + (size_t)n * 32, bsk02, h2, n);

    // layer 3: h3 = relu(conv(h2, W3, b3) + h1@Wsk13 + bsk13)
    gemm_kernel<32, 16, true><<<cdiv(n, 512), 256, 0, stream>>>(h2, W3, dinv, pre, n);
    gemm_kernel<64, 16, false><<<cdiv(n, 512), 256, 0, stream>>>(h1, Wsk13, nullptr,
                                                                 pre + (size_t)n * 16, n);
    gather_combine<16><<<cdiv(n, 4), 256, 0, stream>>>(pre, row_ptr, col, dinv, b3,
                                                       pre + (size_t)n * 16, bsk13, h3, n);

    // final
    final_kernel<<<cdiv(n, 256), 256, 0, stream>>>(h3, Wlin, blin, (float*)d_out, n);
}

// Round 4
// 1425.294 us; speedup vs baseline: 1.2883x; 1.2883x over previous
//
#include <hip/hip_runtime.h>
#include <math.h>

// Tunables for the bucketed CSR build.
// shift=8 -> buckets of 256 nodes; n=200000 -> nb=782 buckets (<=1024).
#define MAXB 1024        // max buckets supported by LDS arrays
#define TILE 4096        // edges per bin_scatter tile
#define SCAT_T 512       // threads in bin_scatter block
#define EPT (TILE / SCAT_T)
#define LCAP 14336       // bucket_csr LDS col capacity (56KB); avg bucket ~8.2k edges

// ---------------- edge dtype detection (int32 vs int64) ----------------

__global__ void detect_kernel(const int* __restrict__ ei, int* __restrict__ flag) {
    int i = threadIdx.x;  // one block of 1024
    if (ei[2 * i + 1] != 0) atomicAdd(flag, 1);
}

__device__ __forceinline__ int load_src(const int* ei, int e, bool is64, int i) {
    return is64 ? ei[2 * i] : ei[i];
}
__device__ __forceinline__ int load_dst(const int* ei, int e, bool is64, int i) {
    return is64 ? ei[2 * e + 2 * i] : ei[e + i];
}

// ---------------- pass 1: per-bucket edge counts ----------------

__global__ __launch_bounds__(256) void bin_count(const int* __restrict__ ei, int e,
                                                 const int* __restrict__ flag, int shift,
                                                 int* __restrict__ gcnt) {
    __shared__ int h[MAXB];
    for (int i = threadIdx.x; i < MAXB; i += 256) h[i] = 0;
    __syncthreads();
    bool is64 = (*flag == 0);
    int stride = gridDim.x * 256;
    for (int i = blockIdx.x * 256 + threadIdx.x; i < e; i += stride) {
        int d = load_dst(ei, e, is64, i);
        atomicAdd(&h[d >> shift], 1);
    }
    __syncthreads();
    for (int i = threadIdx.x; i < MAXB; i += 256)
        if (h[i]) atomicAdd(&gcnt[i], h[i]);
}

// ---------------- pass 2: scan bucket counts -> base, init gcursor ----------------
// single block of 1024 threads, nb <= 1024

__global__ void bin_scan_init(const int* __restrict__ gcnt, int nb,
                              int* __restrict__ base, int* __restrict__ gcursor) {
    __shared__ int sh[1024];
    int t = threadIdx.x;
    int v = (t < nb) ? gcnt[t] : 0;
    sh[t] = v;
    __syncthreads();
    for (int off = 1; off < 1024; off <<= 1) {
        int x = (t >= off) ? sh[t - off] : 0;
        __syncthreads();
        sh[t] += x;
        __syncthreads();
    }
    if (t < nb) {
        int excl = sh[t] - v;
        base[t] = excl;
        gcursor[t] = excl;
        if (t == nb - 1) base[nb] = sh[t];
    }
}

// ---------------- pass 3: tile counting-sort scatter into buckets ----------------
// Packs (src << shift) | (dst & mask) into u32. Writes per tile are grouped by
// bucket -> contiguous runs in the global bucketed array (coalesced-ish).

__global__ __launch_bounds__(SCAT_T) void bin_scatter(const int* __restrict__ ei, int e,
                                                      const int* __restrict__ flag, int shift,
                                                      int* __restrict__ gcursor,
                                                      unsigned int* __restrict__ gpk) {
    __shared__ int hist[MAXB];
    __shared__ int lbase[MAXB];
    __shared__ int gbase[MAXB];
    __shared__ int cur[MAXB];
    __shared__ unsigned int sbuf[TILE];
    __shared__ unsigned short sbkt[TILE];
    __shared__ int sh[SCAT_T];

    const int t = threadIdx.x;
    const int mask = (1 << shift) - 1;
    const bool is64 = (*flag == 0);
    const int tile0 = blockIdx.x * TILE;
    const int cnt = min(TILE, e - tile0);

    for (int i = t; i < MAXB; i += SCAT_T) hist[i] = 0;
    __syncthreads();

    unsigned int pk[EPT];
    int bk[EPT];
#pragma unroll
    for (int k = 0; k < EPT; k++) {
        int g = tile0 + k * SCAT_T + t;
        bk[k] = -1;
        if (g < e) {
            int s = load_src(ei, e, is64, g);
            int d = load_dst(ei, e, is64, g);
            int b = d >> shift;
            pk[k] = ((unsigned int)s << shift) | (unsigned int)(d & mask);
            bk[k] = b;
            atomicAdd(&hist[b], 1);
        }
    }
    __syncthreads();

    // exclusive scan of hist[0..MAXB) using SCAT_T threads, 2 entries each
    {
        int h0 = hist[2 * t];
        int h1 = hist[2 * t + 1];
        int s = h0 + h1;
        sh[t] = s;
        __syncthreads();
        for (int off = 1; off < SCAT_T; off <<= 1) {
            int x = (t >= off) ? sh[t - off] : 0;
            __syncthreads();
            sh[t] += x;
            __syncthreads();
        }
        int excl = sh[t] - s;
        lbase[2 * t] = excl;
        lbase[2 * t + 1] = excl + h0;
    }
    __syncthreads();

    // reserve global space per bucket; init local cursors
    for (int i = t; i < MAXB; i += SCAT_T) {
        int c = hist[i];
        if (c > 0) gbase[i] = atomicAdd(&gcursor[i], c);
        cur[i] = lbase[i];
    }
    __syncthreads();

    // place into LDS staging grouped by bucket
#pragma unroll
    for (int k = 0; k < EPT; k++) {
        if (bk[k] >= 0) {
            int p = atomicAdd(&cur[bk[k]], 1);
            sbuf[p] = pk[k];
            sbkt[p] = (unsigned short)bk[k];
        }
    }
    __syncthreads();

    // flush: each bucket's run is contiguous in LDS and in global
    for (int i = t; i < cnt; i += SCAT_T) {
        int b = sbkt[i];
        gpk[gbase[b] + (i - lbase[b])] = sbuf[i];
    }
}

// ---------------- pass 4: per-bucket degree + dinv (coalesced) ----------------

__global__ __launch_bounds__(256) void bucket_deg(const unsigned int* __restrict__ gpk,
                                                  const int* __restrict__ base, int shift,
                                                  int n, int* __restrict__ deg,
                                                  float* __restrict__ dinv) {
    __shared__ int dc[MAXB];  // per-node counts within bucket (bucket size <= 1024)
    int b = blockIdx.x;
    int mask = (1 << shift) - 1;
    int node0 = b << shift;
    int nc = min(1 << shift, n - node0);
    for (int i = threadIdx.x; i < (1 << shift); i += 256) dc[i] = 0;
    __syncthreads();
    int lo = base[b], hi = base[b + 1];
    for (int j = lo + threadIdx.x; j < hi; j += 256)
        atomicAdd(&dc[gpk[j] & mask], 1);
    __syncthreads();
    for (int i = threadIdx.x; i < nc; i += 256) {
        int d = dc[i];
        deg[node0 + i] = d;
        dinv[node0 + i] = rsqrtf(1.0f + (float)d);
    }
}

// ---------------- row_ptr scan over deg (unchanged machinery) ----------------

__global__ void scan_partial(const int* __restrict__ deg, int* __restrict__ out,
                             int* __restrict__ bsums, int n) {
    __shared__ int sh[256];
    int t = threadIdx.x;
    int base = blockIdx.x * 1024 + t * 4;
    int v0 = 0, v1 = 0, v2 = 0, v3 = 0;
    if (base + 0 < n) v0 = deg[base + 0];
    if (base + 1 < n) v1 = deg[base + 1];
    if (base + 2 < n) v2 = deg[base + 2];
    if (base + 3 < n) v3 = deg[base + 3];
    int s = v0 + v1 + v2 + v3;
    sh[t] = s;
    __syncthreads();
    for (int off = 1; off < 256; off <<= 1) {
        int x = (t >= off) ? sh[t - off] : 0;
        __syncthreads();
        sh[t] += x;
        __syncthreads();
    }
    int excl = sh[t] - s;
    if (base + 0 < n) out[base + 0] = excl;  excl += v0;
    if (base + 1 < n) out[base + 1] = excl;  excl += v1;
    if (base + 2 < n) out[base + 2] = excl;  excl += v2;
    if (base + 3 < n) out[base + 3] = excl;
    if (t == 255) bsums[blockIdx.x] = sh[255];
}

__global__ void scan_bsums(int* bsums, int nb) {
    __shared__ int sh[1024];
    int t = threadIdx.x;
    sh[t] = (t < nb) ? bsums[t] : 0;
    __syncthreads();
    for (int off = 1; off < 1024; off <<= 1) {
        int x = (t >= off) ? sh[t - off] : 0;
        __syncthreads();
        sh[t] += x;
        __syncthreads();
    }
    if (t < nb) bsums[t] = sh[t];
}

__global__ void scan_add(int* __restrict__ row_ptr, const int* __restrict__ bsums,
                         int n, int nb) {
    int i = blockIdx.x * blockDim.x + threadIdx.x;
    if (i < n) {
        int b = i >> 10;
        if (b > 0) row_ptr[i] += bsums[b - 1];
    } else if (i == n) {
        row_ptr[n] = bsums[nb - 1];
    }
}

// ---------------- pass 5: per-bucket exact CSR build in LDS ----------------

__global__ __launch_bounds__(256) void bucket_csr(const unsigned int* __restrict__ gpk,
                                                  const int* __restrict__ base,
                                                  const int* __restrict__ row_ptr, int shift,
                                                  int n, int* __restrict__ col) {
    __shared__ int lcol[LCAP];
    __shared__ int cur[MAXB];
    int b = blockIdx.x;
    int mask = (1 << shift) - 1;
    int node0 = b << shift;
    int nc = min(1 << shift, n - node0);
    int rstart = row_ptr[node0];
    for (int i = threadIdx.x; i < nc; i += 256)
        cur[i] = row_ptr[node0 + i] - rstart;
    __syncthreads();
    int lo = base[b], hi = base[b + 1];
    int ecnt = hi - lo;
    if (ecnt <= LCAP) {
        for (int j = lo + threadIdx.x; j < hi; j += 256) {
            unsigned int v = gpk[j];
            int p = atomicAdd(&cur[v & mask], 1);
            lcol[p] = (int)(v >> shift);
        }
        __syncthreads();
        for (int j = threadIdx.x; j < ecnt; j += 256)
            col[rstart + j] = lcol[j];
    } else {  // overflow fallback (never for random graphs): direct scatter
        for (int j = lo + threadIdx.x; j < hi; j += 256) {
            unsigned int v = gpk[j];
            int p = atomicAdd(&cur[v & mask], 1);
            col[rstart + p] = (int)(v >> shift);
        }
    }
}

// ---------------- GEMM: out[n,CO] = A[n,CI] @ W[CI,CO], optional *dinv[row] ----------------

template <int CI, int CO, bool SCALE>
__global__ __launch_bounds__(256) void gemm_kernel(const float* __restrict__ A,
                                                   const float* __restrict__ W,
                                                   const float* __restrict__ dinv,
                                                   float* __restrict__ out, int n) {
    constexpr int CT = CO / 4;
    constexpr int RG = 256 / CT;
    constexpr int BR = RG * 8;
    __shared__ __align__(16) float Wl[CI * CO];
    for (int i = threadIdx.x; i < CI * CO; i += 256) Wl[i] = W[i];
    __syncthreads();

    int ct = threadIdx.x % CT;
    int rg = threadIdx.x / CT;
    int c0 = ct * 4;
    int row0 = blockIdx.x * BR + rg * 8;

    float acc[8][4] = {{0.f}};
    for (int k = 0; k < CI; k += 4) {
        float4 a[8];
#pragma unroll
        for (int r = 0; r < 8; r++) {
            int row = row0 + r;
            if (row < n)
                a[r] = *reinterpret_cast<const float4*>(&A[row * CI + k]);
            else
                a[r] = float4{0.f, 0.f, 0.f, 0.f};
        }
#pragma unroll
        for (int kk = 0; kk < 4; kk++) {
            float4 w = *reinterpret_cast<const float4*>(&Wl[(k + kk) * CO + c0]);
#pragma unroll
            for (int r = 0; r < 8; r++) {
                float av = (kk == 0) ? a[r].x : (kk == 1) ? a[r].y : (kk == 2) ? a[r].z : a[r].w;
                acc[r][0] += av * w.x;
                acc[r][1] += av * w.y;
                acc[r][2] += av * w.z;
                acc[r][3] += av * w.w;
            }
        }
    }
#pragma unroll
    for (int r = 0; r < 8; r++) {
        int row = row0 + r;
        if (row >= n) continue;
        float s = SCALE ? dinv[row] : 1.0f;
        float4 o{acc[r][0] * s, acc[r][1] * s, acc[r][2] * s, acc[r][3] * s};
        *reinterpret_cast<float4*>(&out[row * CO + c0]) = o;
    }
}

// ---------------- Fused gather + self-loop + bias + skip + relu ----------------
// ONE WAVE PER NODE; grid is always cdiv(n,4) with 256-thread blocks.

template <int F>
__global__ __launch_bounds__(256) void gather_combine(
    const float* __restrict__ hs, const int* __restrict__ row_ptr,
    const int* __restrict__ col, const float* __restrict__ dinv,
    const float* __restrict__ bias, const float* __restrict__ sk,
    const float* __restrict__ bsk, float* __restrict__ out, int n) {
    constexpr int EPI = 64 / F;
    int wid = (blockIdx.x * blockDim.x + threadIdx.x) >> 6;
    int lane = threadIdx.x & 63;
    if (wid >= n) return;
    int sub = lane / F;
    int f = lane & (F - 1);
    int start = row_ptr[wid];
    int end = row_ptr[wid + 1];

    float acc = 0.f;
    int j = start + sub;
    while (j + EPI < end) {
        int c0 = col[j];
        int c1 = col[j + EPI];
        float va = hs[c0 * F + f];
        float vb = hs[c1 * F + f];
        acc += va;
        acc += vb;
        j += 2 * EPI;
    }
    if (j < end) acc += hs[col[j] * F + f];

    if (F <= 32) acc += __shfl_xor(acc, 32);
    if (F <= 16) acc += __shfl_xor(acc, 16);

    float dn = dinv[wid];
    if (lane < F) {
        float v = dn * acc + hs[wid * F + f] * dn + bias[f];
        if (sk) v += sk[wid * F + f] + bsk[f];
        out[wid * F + f] = fmaxf(v, 0.f);
    }
}

// ---------------- Final: out[n] = sigmoid(h3[n,:16] @ Wlin + blin) ----------------

__global__ void final_kernel(const float* __restrict__ h3, const float* __restrict__ Wlin,
                             const float* __restrict__ blin, float* __restrict__ out, int n) {
    int i = blockIdx.x * blockDim.x + threadIdx.x;
    if (i >= n) return;
    float s = blin[0];
#pragma unroll
    for (int f = 0; f < 16; f++) s += h3[i * 16 + f] * Wlin[f];
    out[i] = 1.0f / (1.0f + expf(-s));
}

// ---------------- launch ----------------

extern "C" void kernel_launch(void* const* d_in, const int* in_sizes, int n_in,
                              void* d_out, int out_size, void* d_ws, size_t ws_size,
                              hipStream_t stream) {
    const float* x     = (const float*)d_in[0];
    const int*   ei    = (const int*)d_in[1];
    const float* W1    = (const float*)d_in[2];
    const float* b1    = (const float*)d_in[3];
    const float* W2    = (const float*)d_in[4];
    const float* b2    = (const float*)d_in[5];
    const float* W3    = (const float*)d_in[6];
    const float* b3    = (const float*)d_in[7];
    const float* Wsk02 = (const float*)d_in[8];
    const float* bsk02 = (const float*)d_in[9];
    const float* Wsk13 = (const float*)d_in[10];
    const float* bsk13 = (const float*)d_in[11];
    const float* Wlin  = (const float*)d_in[12];
    const float* blin  = (const float*)d_in[13];

    const int n = in_sizes[0] / 128;
    const int e = in_sizes[1] / 2;

    // bucket shift: buckets of 256 nodes; grow if n would exceed MAXB buckets
    int shift = 8;
    while (((n + (1 << shift) - 1) >> shift) > MAXB) shift++;
    const int nbkt = (n + (1 << shift) - 1) >> shift;

    // workspace carve (256B aligned)
    char* p = (char*)d_ws;
    auto alloc = [&](size_t bytes) {
        void* r = (void*)p;
        p += (bytes + 255) / 256 * 256;
        return r;
    };
    int*   flag    = (int*)alloc(256);
    int*   gcnt    = (int*)alloc(MAXB * 4);
    int*   base    = (int*)alloc((MAXB + 1) * 4);
    int*   gcursor = (int*)alloc(MAXB * 4);
    int*   bsums   = (int*)alloc(4096);
    int*   deg     = (int*)alloc((size_t)n * 4);
    int*   row_ptr = (int*)alloc((size_t)(n + 1) * 4);
    float* dinv    = (float*)alloc((size_t)n * 4);
    int*   col     = (int*)alloc((size_t)e * 4);
    float* h1      = (float*)alloc((size_t)n * 64 * 4);
    float* h2      = (float*)alloc((size_t)n * 32 * 4);
    float* h3      = (float*)alloc((size_t)n * 16 * 4);
    float* pre     = (float*)alloc((size_t)n * 64 * 4);  // reused: gpk | gemm outputs
    unsigned int* gpk = (unsigned int*)pre;  // dead before first GEMM writes pre

    auto cdiv = [](int a, int b) { return (a + b - 1) / b; };

    // CSR build (bucketed counting sort; all coalesced-ish I/O)
    hipMemsetAsync(flag, 0, 4, stream);
    hipMemsetAsync(gcnt, 0, MAXB * 4, stream);
    detect_kernel<<<1, 1024, 0, stream>>>(ei, flag);
    bin_count<<<1024, 256, 0, stream>>>(ei, e, flag, shift, gcnt);
    bin_scan_init<<<1, 1024, 0, stream>>>(gcnt, nbkt, base, gcursor);
    bin_scatter<<<cdiv(e, TILE), SCAT_T, 0, stream>>>(ei, e, flag, shift, gcursor, gpk);
    bucket_deg<<<nbkt, 256, 0, stream>>>(gpk, base, shift, n, deg, dinv);
    scan_partial<<<cdiv(n, 1024), 256, 0, stream>>>(deg, row_ptr, bsums, n);
    scan_bsums<<<1, 1024, 0, stream>>>(bsums, cdiv(n, 1024));
    scan_add<<<cdiv(n + 1, 256), 256, 0, stream>>>(row_ptr, bsums, n, cdiv(n, 1024));
    bucket_csr<<<nbkt, 256, 0, stream>>>(gpk, base, row_ptr, shift, n, col);

    // layer 1: h1 = relu(conv(x, W1, b1))
    gemm_kernel<128, 64, true><<<cdiv(n, 128), 256, 0, stream>>>(x, W1, dinv, pre, n);
    gather_combine<64><<<cdiv(n, 4), 256, 0, stream>>>(pre, row_ptr, col, dinv, b1,
                                                       nullptr, nullptr, h1, n);

    // layer 2: h2 = relu(conv(h1, W2, b2) + x@Wsk02 + bsk02)
    gemm_kernel<64, 32, true><<<cdiv(n, 256), 256, 0, stream>>>(h1, W2, dinv, pre, n);
    gemm_kernel<128, 32, false><<<cdiv(n, 256), 256, 0, stream>>>(x, Wsk02, nullptr,
                                                                  pre + (size_t)n * 32, n);
    gather_combine<32><<<cdiv(n, 4), 256, 0, stream>>>(pre, row_ptr, col, dinv, b2,
                                                       pre + (size_t)n * 32, bsk02, h2, n);

    // layer 3: h3 = relu(conv(h2, W3, b3) + h1@Wsk13 + bsk13)
    gemm_kernel<32, 16, true><<<cdiv(n, 512), 256, 0, stream>>>(h2, W3, dinv, pre, n);
    gemm_kernel<64, 16, false><<<cdiv(n, 512), 256, 0, stream>>>(h1, Wsk13, nullptr,
                                                                 pre + (size_t)n * 16, n);
    gather_combine<16><<<cdiv(n, 4), 256, 0, stream>>>(pre, row_ptr, col, dinv, b3,
                                                       pre + (size_t)n * 16, bsk13, h3, n);

    // final
    final_kernel<<<cdiv(n, 256), 256, 0, stream>>>(h3, Wlin, blin, (float*)d_out, n);
}

// Round 5
// 1231.294 us; speedup vs baseline: 1.4912x; 1.1576x over previous
//
#include <hip/hip_runtime.h>
#include <hip/hip_fp16.h>
#include <math.h>

// Tunables for the bucketed CSR build.
#define MAXB 1024        // max buckets supported by LDS arrays
#define TILE 4096        // edges per bin_scatter tile
#define SCAT_T 512       // threads in bin_scatter block
#define EPT (TILE / SCAT_T)
#define LCAP 14336       // bucket_csr LDS col capacity (56KB)

// ---------------- fp16 pack helpers ----------------

__device__ __forceinline__ unsigned int pack_f16(float a, float b) {
    __half2 h = __floats2half2_rn(a, b);
    return *reinterpret_cast<unsigned int*>(&h);
}
__device__ __forceinline__ float f16_lo(unsigned int u) {
    __half2 h = *reinterpret_cast<__half2*>(&u);
    return __low2float(h);
}
__device__ __forceinline__ float f16_hi(unsigned int u) {
    __half2 h = *reinterpret_cast<__half2*>(&u);
    return __high2float(h);
}

// ---------------- edge dtype detection (int32 vs int64) ----------------

__global__ void detect_kernel(const int* __restrict__ ei, int* __restrict__ flag) {
    int i = threadIdx.x;  // one block of 1024
    if (ei[2 * i + 1] != 0) atomicAdd(flag, 1);
}

__device__ __forceinline__ int load_src(const int* ei, int e, bool is64, int i) {
    return is64 ? ei[2 * i] : ei[i];
}
__device__ __forceinline__ int load_dst(const int* ei, int e, bool is64, int i) {
    return is64 ? ei[2 * e + 2 * i] : ei[e + i];
}

// ---------------- pass 1: per-bucket edge counts ----------------

__global__ __launch_bounds__(256) void bin_count(const int* __restrict__ ei, int e,
                                                 const int* __restrict__ flag, int shift,
                                                 int* __restrict__ gcnt) {
    __shared__ int h[MAXB];
    for (int i = threadIdx.x; i < MAXB; i += 256) h[i] = 0;
    __syncthreads();
    bool is64 = (*flag == 0);
    int stride = gridDim.x * 256;
    for (int i = blockIdx.x * 256 + threadIdx.x; i < e; i += stride) {
        int d = load_dst(ei, e, is64, i);
        atomicAdd(&h[d >> shift], 1);
    }
    __syncthreads();
    for (int i = threadIdx.x; i < MAXB; i += 256)
        if (h[i]) atomicAdd(&gcnt[i], h[i]);
}

// ---------------- pass 2: scan bucket counts -> base, init gcursor ----------------

__global__ void bin_scan_init(const int* __restrict__ gcnt, int nb,
                              int* __restrict__ base, int* __restrict__ gcursor) {
    __shared__ int sh[1024];
    int t = threadIdx.x;
    int v = (t < nb) ? gcnt[t] : 0;
    sh[t] = v;
    __syncthreads();
    for (int off = 1; off < 1024; off <<= 1) {
        int x = (t >= off) ? sh[t - off] : 0;
        __syncthreads();
        sh[t] += x;
        __syncthreads();
    }
    if (t < nb) {
        int excl = sh[t] - v;
        base[t] = excl;
        gcursor[t] = excl;
        if (t == nb - 1) base[nb] = sh[t];
    }
}

// ---------------- pass 3: tile counting-sort scatter into buckets ----------------

__global__ __launch_bounds__(SCAT_T) void bin_scatter(const int* __restrict__ ei, int e,
                                                      const int* __restrict__ flag, int shift,
                                                      int* __restrict__ gcursor,
                                                      unsigned int* __restrict__ gpk) {
    __shared__ int hist[MAXB];
    __shared__ int lbase[MAXB];
    __shared__ int gbase[MAXB];
    __shared__ int cur[MAXB];
    __shared__ unsigned int sbuf[TILE];
    __shared__ unsigned short sbkt[TILE];
    __shared__ int sh[SCAT_T];

    const int t = threadIdx.x;
    const int mask = (1 << shift) - 1;
    const bool is64 = (*flag == 0);
    const int tile0 = blockIdx.x * TILE;
    const int cnt = min(TILE, e - tile0);

    for (int i = t; i < MAXB; i += SCAT_T) hist[i] = 0;
    __syncthreads();

    unsigned int pk[EPT];
    int bk[EPT];
#pragma unroll
    for (int k = 0; k < EPT; k++) {
        int g = tile0 + k * SCAT_T + t;
        bk[k] = -1;
        if (g < e) {
            int s = load_src(ei, e, is64, g);
            int d = load_dst(ei, e, is64, g);
            int b = d >> shift;
            pk[k] = ((unsigned int)s << shift) | (unsigned int)(d & mask);
            bk[k] = b;
            atomicAdd(&hist[b], 1);
        }
    }
    __syncthreads();

    {
        int h0 = hist[2 * t];
        int h1 = hist[2 * t + 1];
        int s = h0 + h1;
        sh[t] = s;
        __syncthreads();
        for (int off = 1; off < SCAT_T; off <<= 1) {
            int x = (t >= off) ? sh[t - off] : 0;
            __syncthreads();
            sh[t] += x;
            __syncthreads();
        }
        int excl = sh[t] - s;
        lbase[2 * t] = excl;
        lbase[2 * t + 1] = excl + h0;
    }
    __syncthreads();

    for (int i = t; i < MAXB; i += SCAT_T) {
        int c = hist[i];
        if (c > 0) gbase[i] = atomicAdd(&gcursor[i], c);
        cur[i] = lbase[i];
    }
    __syncthreads();

#pragma unroll
    for (int k = 0; k < EPT; k++) {
        if (bk[k] >= 0) {
            int p = atomicAdd(&cur[bk[k]], 1);
            sbuf[p] = pk[k];
            sbkt[p] = (unsigned short)bk[k];
        }
    }
    __syncthreads();

    for (int i = t; i < cnt; i += SCAT_T) {
        int b = sbkt[i];
        gpk[gbase[b] + (i - lbase[b])] = sbuf[i];
    }
}

// ---------------- pass 4: per-bucket degree + dinv (coalesced) ----------------

__global__ __launch_bounds__(256) void bucket_deg(const unsigned int* __restrict__ gpk,
                                                  const int* __restrict__ base, int shift,
                                                  int n, int* __restrict__ deg,
                                                  float* __restrict__ dinv) {
    __shared__ int dc[MAXB];
    int b = blockIdx.x;
    int mask = (1 << shift) - 1;
    int node0 = b << shift;
    int nc = min(1 << shift, n - node0);
    for (int i = threadIdx.x; i < (1 << shift); i += 256) dc[i] = 0;
    __syncthreads();
    int lo = base[b], hi = base[b + 1];
    for (int j = lo + threadIdx.x; j < hi; j += 256)
        atomicAdd(&dc[gpk[j] & mask], 1);
    __syncthreads();
    for (int i = threadIdx.x; i < nc; i += 256) {
        int d = dc[i];
        deg[node0 + i] = d;
        dinv[node0 + i] = rsqrtf(1.0f + (float)d);
    }
}

// ---------------- row_ptr scan over deg ----------------

__global__ void scan_partial(const int* __restrict__ deg, int* __restrict__ out,
                             int* __restrict__ bsums, int n) {
    __shared__ int sh[256];
    int t = threadIdx.x;
    int base = blockIdx.x * 1024 + t * 4;
    int v0 = 0, v1 = 0, v2 = 0, v3 = 0;
    if (base + 0 < n) v0 = deg[base + 0];
    if (base + 1 < n) v1 = deg[base + 1];
    if (base + 2 < n) v2 = deg[base + 2];
    if (base + 3 < n) v3 = deg[base + 3];
    int s = v0 + v1 + v2 + v3;
    sh[t] = s;
    __syncthreads();
    for (int off = 1; off < 256; off <<= 1) {
        int x = (t >= off) ? sh[t - off] : 0;
        __syncthreads();
        sh[t] += x;
        __syncthreads();
    }
    int excl = sh[t] - s;
    if (base + 0 < n) out[base + 0] = excl;  excl += v0;
    if (base + 1 < n) out[base + 1] = excl;  excl += v1;
    if (base + 2 < n) out[base + 2] = excl;  excl += v2;
    if (base + 3 < n) out[base + 3] = excl;
    if (t == 255) bsums[blockIdx.x] = sh[255];
}

__global__ void scan_bsums(int* bsums, int nb) {
    __shared__ int sh[1024];
    int t = threadIdx.x;
    sh[t] = (t < nb) ? bsums[t] : 0;
    __syncthreads();
    for (int off = 1; off < 1024; off <<= 1) {
        int x = (t >= off) ? sh[t - off] : 0;
        __syncthreads();
        sh[t] += x;
        __syncthreads();
    }
    if (t < nb) bsums[t] = sh[t];
}

__global__ void scan_add(int* __restrict__ row_ptr, const int* __restrict__ bsums,
                         int n, int nb) {
    int i = blockIdx.x * blockDim.x + threadIdx.x;
    if (i < n) {
        int b = i >> 10;
        if (b > 0) row_ptr[i] += bsums[b - 1];
    } else if (i == n) {
        row_ptr[n] = bsums[nb - 1];
    }
}

// ---------------- pass 5: per-bucket exact CSR build in LDS ----------------

__global__ __launch_bounds__(256) void bucket_csr(const unsigned int* __restrict__ gpk,
                                                  const int* __restrict__ base,
                                                  const int* __restrict__ row_ptr, int shift,
                                                  int n, int* __restrict__ col) {
    __shared__ int lcol[LCAP];
    __shared__ int cur[MAXB];
    int b = blockIdx.x;
    int mask = (1 << shift) - 1;
    int node0 = b << shift;
    int nc = min(1 << shift, n - node0);
    int rstart = row_ptr[node0];
    for (int i = threadIdx.x; i < nc; i += 256)
        cur[i] = row_ptr[node0 + i] - rstart;
    __syncthreads();
    int lo = base[b], hi = base[b + 1];
    int ecnt = hi - lo;
    if (ecnt <= LCAP) {
        for (int j = lo + threadIdx.x; j < hi; j += 256) {
            unsigned int v = gpk[j];
            int p = atomicAdd(&cur[v & mask], 1);
            lcol[p] = (int)(v >> shift);
        }
        __syncthreads();
        for (int j = threadIdx.x; j < ecnt; j += 256)
            col[rstart + j] = lcol[j];
    } else {
        for (int j = lo + threadIdx.x; j < hi; j += 256) {
            unsigned int v = gpk[j];
            int p = atomicAdd(&cur[v & mask], 1);
            col[rstart + p] = (int)(v >> shift);
        }
    }
}

// ---------------- GEMM: out[n,CO] = A[n,CI] @ W[CI,CO] ----------------
// SCALE: multiply row by dinv[row]. BF16OUT(=fp16 packed): write packed half2
// words (for the gather table); else fp32.

template <int CI, int CO, bool SCALE, bool PACKOUT>
__global__ __launch_bounds__(256) void gemm_kernel(const float* __restrict__ A,
                                                   const float* __restrict__ W,
                                                   const float* __restrict__ dinv,
                                                   void* __restrict__ outv, int n) {
    constexpr int CT = CO / 4;
    constexpr int RG = 256 / CT;
    constexpr int BR = RG * 8;
    __shared__ __align__(16) float Wl[CI * CO];
    for (int i = threadIdx.x; i < CI * CO; i += 256) Wl[i] = W[i];
    __syncthreads();

    int ct = threadIdx.x % CT;
    int rg = threadIdx.x / CT;
    int c0 = ct * 4;
    int row0 = blockIdx.x * BR + rg * 8;

    float acc[8][4] = {{0.f}};
    for (int k = 0; k < CI; k += 4) {
        float4 a[8];
#pragma unroll
        for (int r = 0; r < 8; r++) {
            int row = row0 + r;
            if (row < n)
                a[r] = *reinterpret_cast<const float4*>(&A[row * CI + k]);
            else
                a[r] = float4{0.f, 0.f, 0.f, 0.f};
        }
#pragma unroll
        for (int kk = 0; kk < 4; kk++) {
            float4 w = *reinterpret_cast<const float4*>(&Wl[(k + kk) * CO + c0]);
#pragma unroll
            for (int r = 0; r < 8; r++) {
                float av = (kk == 0) ? a[r].x : (kk == 1) ? a[r].y : (kk == 2) ? a[r].z : a[r].w;
                acc[r][0] += av * w.x;
                acc[r][1] += av * w.y;
                acc[r][2] += av * w.z;
                acc[r][3] += av * w.w;
            }
        }
    }
#pragma unroll
    for (int r = 0; r < 8; r++) {
        int row = row0 + r;
        if (row >= n) continue;
        float s = SCALE ? dinv[row] : 1.0f;
        if (PACKOUT) {
            unsigned int* o = (unsigned int*)outv;
            uint2 pk{pack_f16(acc[r][0] * s, acc[r][1] * s),
                     pack_f16(acc[r][2] * s, acc[r][3] * s)};
            *reinterpret_cast<uint2*>(&o[(size_t)row * (CO / 2) + ct * 2]) = pk;
        } else {
            float* o = (float*)outv;
            float4 v{acc[r][0] * s, acc[r][1] * s, acc[r][2] * s, acc[r][3] * s};
            *reinterpret_cast<float4*>(&o[(size_t)row * CO + c0]) = v;
        }
    }
}

// ---------------- Fused gather (fp16 table) + self-loop + bias + skip + relu ----------------
// ONE WAVE PER NODE; grid = cdiv(n,4) with 256-thread blocks.
// hp[n, F/2] holds packed fp16 pre-scaled features (pre = (A@W)*dinv).
// Each lane covers 2 features; an edge needs PF=F/2 lanes; EPW=64/PF edges
// are processed concurrently per wave (2/4/8 for F=64/32/16), 2x unrolled.

template <int F>
__global__ __launch_bounds__(256) void gather_combine(
    const unsigned int* __restrict__ hp, const int* __restrict__ row_ptr,
    const int* __restrict__ col, const float* __restrict__ dinv,
    const float* __restrict__ bias, const float* __restrict__ sk,
    const float* __restrict__ bsk, float* __restrict__ out, int n) {
    constexpr int PF = F / 2;
    constexpr int EPW = 64 / PF;
    int wid = (blockIdx.x * blockDim.x + threadIdx.x) >> 6;
    int lane = threadIdx.x & 63;
    if (wid >= n) return;
    int sub = lane / PF;
    int fp = lane & (PF - 1);
    int start = row_ptr[wid];
    int end = row_ptr[wid + 1];

    float a0 = 0.f, a1 = 0.f;
    int j = start + sub;
    while (j + EPW < end) {
        int c0 = col[j];
        int c1 = col[j + EPW];
        unsigned int u0 = hp[(size_t)c0 * PF + fp];
        unsigned int u1 = hp[(size_t)c1 * PF + fp];
        a0 += f16_lo(u0); a1 += f16_hi(u0);
        a0 += f16_lo(u1); a1 += f16_hi(u1);
        j += 2 * EPW;
    }
    if (j < end) {
        unsigned int u = hp[(size_t)col[j] * PF + fp];
        a0 += f16_lo(u); a1 += f16_hi(u);
    }

#pragma unroll
    for (int m = PF; m < 64; m <<= 1) {
        a0 += __shfl_xor(a0, m);
        a1 += __shfl_xor(a1, m);
    }

    if (lane < PF) {
        float dn = dinv[wid];
        unsigned int us = hp[(size_t)wid * PF + fp];
        float v0 = dn * a0 + f16_lo(us) * dn + bias[2 * fp];
        float v1 = dn * a1 + f16_hi(us) * dn + bias[2 * fp + 1];
        if (sk) {
            float2 s2 = *reinterpret_cast<const float2*>(&sk[(size_t)wid * F + 2 * fp]);
            v0 += s2.x + bsk[2 * fp];
            v1 += s2.y + bsk[2 * fp + 1];
        }
        float2 o{fmaxf(v0, 0.f), fmaxf(v1, 0.f)};
        *reinterpret_cast<float2*>(&out[(size_t)wid * F + 2 * fp]) = o;
    }
}

// ---------------- Final: out[n] = sigmoid(h3[n,:16] @ Wlin + blin) ----------------

__global__ void final_kernel(const float* __restrict__ h3, const float* __restrict__ Wlin,
                             const float* __restrict__ blin, float* __restrict__ out, int n) {
    int i = blockIdx.x * blockDim.x + threadIdx.x;
    if (i >= n) return;
    float s = blin[0];
#pragma unroll
    for (int f = 0; f < 16; f++) s += h3[i * 16 + f] * Wlin[f];
    out[i] = 1.0f / (1.0f + expf(-s));
}

// ---------------- launch ----------------

extern "C" void kernel_launch(void* const* d_in, const int* in_sizes, int n_in,
                              void* d_out, int out_size, void* d_ws, size_t ws_size,
                              hipStream_t stream) {
    const float* x     = (const float*)d_in[0];
    const int*   ei    = (const int*)d_in[1];
    const float* W1    = (const float*)d_in[2];
    const float* b1    = (const float*)d_in[3];
    const float* W2    = (const float*)d_in[4];
    const float* b2    = (const float*)d_in[5];
    const float* W3    = (const float*)d_in[6];
    const float* b3    = (const float*)d_in[7];
    const float* Wsk02 = (const float*)d_in[8];
    const float* bsk02 = (const float*)d_in[9];
    const float* Wsk13 = (const float*)d_in[10];
    const float* bsk13 = (const float*)d_in[11];
    const float* Wlin  = (const float*)d_in[12];
    const float* blin  = (const float*)d_in[13];

    const int n = in_sizes[0] / 128;
    const int e = in_sizes[1] / 2;

    int shift = 8;
    while (((n + (1 << shift) - 1) >> shift) > MAXB) shift++;
    const int nbkt = (n + (1 << shift) - 1) >> shift;

    // workspace carve (256B aligned)
    char* p = (char*)d_ws;
    auto alloc = [&](size_t bytes) {
        void* r = (void*)p;
        p += (bytes + 255) / 256 * 256;
        return r;
    };
    int*   flag    = (int*)alloc(256);
    int*   gcnt    = (int*)alloc(MAXB * 4);
    int*   base    = (int*)alloc((MAXB + 1) * 4);
    int*   gcursor = (int*)alloc(MAXB * 4);
    int*   bsums   = (int*)alloc(4096);
    int*   deg     = (int*)alloc((size_t)n * 4);
    int*   row_ptr = (int*)alloc((size_t)(n + 1) * 4);
    float* dinv    = (float*)alloc((size_t)n * 4);
    int*   col     = (int*)alloc((size_t)e * 4);
    float* h1      = (float*)alloc((size_t)n * 64 * 4);
    float* h2      = (float*)alloc((size_t)n * 32 * 4);
    float* h3      = (float*)alloc((size_t)n * 16 * 4);
    float* sk      = (float*)alloc((size_t)n * 32 * 4);              // fp32 skip buffer
    size_t prebytes = (size_t)(e > n * 32 ? e : n * 32) * 4;
    unsigned int* preb = (unsigned int*)alloc(prebytes);             // fp16-packed gather table
    unsigned int* gpk  = preb;  // bucketed packed edges; dead before GEMM1 writes preb

    auto cdiv = [](int a, int b) { return (a + b - 1) / b; };

    // CSR build
    hipMemsetAsync(flag, 0, 4, stream);
    hipMemsetAsync(gcnt, 0, MAXB * 4, stream);
    detect_kernel<<<1, 1024, 0, stream>>>(ei, flag);
    bin_count<<<1024, 256, 0, stream>>>(ei, e, flag, shift, gcnt);
    bin_scan_init<<<1, 1024, 0, stream>>>(gcnt, nbkt, base, gcursor);
    bin_scatter<<<cdiv(e, TILE), SCAT_T, 0, stream>>>(ei, e, flag, shift, gcursor, gpk);
    bucket_deg<<<nbkt, 256, 0, stream>>>(gpk, base, shift, n, deg, dinv);
    scan_partial<<<cdiv(n, 1024), 256, 0, stream>>>(deg, row_ptr, bsums, n);
    scan_bsums<<<1, 1024, 0, stream>>>(bsums, cdiv(n, 1024));
    scan_add<<<cdiv(n + 1, 256), 256, 0, stream>>>(row_ptr, bsums, n, cdiv(n, 1024));
    bucket_csr<<<nbkt, 256, 0, stream>>>(gpk, base, row_ptr, shift, n, col);

    // layer 1: h1 = relu(conv(x, W1, b1))
    gemm_kernel<128, 64, true, true><<<cdiv(n, 128), 256, 0, stream>>>(x, W1, dinv, preb, n);
    gather_combine<64><<<cdiv(n, 4), 256, 0, stream>>>(preb, row_ptr, col, dinv, b1,
                                                       nullptr, nullptr, h1, n);

    // layer 2: h2 = relu(conv(h1, W2, b2) + x@Wsk02 + bsk02)
    gemm_kernel<64, 32, true, true><<<cdiv(n, 256), 256, 0, stream>>>(h1, W2, dinv, preb, n);
    gemm_kernel<128, 32, false, false><<<cdiv(n, 256), 256, 0, stream>>>(x, Wsk02, nullptr, sk, n);
    gather_combine<32><<<cdiv(n, 4), 256, 0, stream>>>(preb, row_ptr, col, dinv, b2,
                                                       sk, bsk02, h2, n);

    // layer 3: h3 = relu(conv(h2, W3, b3) + h1@Wsk13 + bsk13)
    gemm_kernel<32, 16, true, true><<<cdiv(n, 512), 256, 0, stream>>>(h2, W3, dinv, preb, n);
    gemm_kernel<64, 16, false, false><<<cdiv(n, 512), 256, 0, stream>>>(h1, Wsk13, nullptr, sk, n);
    gather_combine<16><<<cdiv(n, 4), 256, 0, stream>>>(preb, row_ptr, col, dinv, b3,
                                                       sk, bsk13, h3, n);

    // final
    final_kernel<<<cdiv(n, 256), 256, 0, stream>>>(h3, Wlin, blin, (float*)d_out, n);
}